// Round 2
// 251.099 us; speedup vs baseline: 1.0808x; 1.0808x over previous
//
#include <hip/hip_runtime.h>
#include <math.h>

#define BATCH 256
#define PRE   64     // k
#define NEXT  32     // K
#define DIN   128    // d
#define DOUT  64     // D

typedef __attribute__((ext_vector_type(8))) short bf16x8;
typedef __attribute__((ext_vector_type(4))) float f32x4;

__device__ __forceinline__ unsigned short f2bf(float f) {
    unsigned u = __float_as_uint(f);
    unsigned r = (u + 0x7fffu + ((u >> 16) & 1u)) >> 16;   // RNE
    return (unsigned short)r;
}
__device__ __forceinline__ float bf2f(unsigned short h) {
    return __uint_as_float(((unsigned)h) << 16);
}

#define WFRAG_S 10   // dwords per fragment slot (8 data + 2 pad)

// ---------------- MFMA GEMM -> p fp32, NATURAL [lb,k,K,D] layout --------------
// (unchanged from the verified 272us version; fp16 p failed correctness by 5x
//  -- softmax amplifies logit quantization through 3 routing iterations)
__global__ __launch_bounds__(256, 2) void gemm_kernel(const float* __restrict__ x,
                                                      const float* __restrict__ W,
                                                      float* __restrict__ p,
                                                      int b0)
{
    __shared__ float xs[128 * 40];              // 20.5 KB x-tile [row][d]
    __shared__ unsigned wpk[256 * WFRAG_S];     // 10 KB packed W frags
    const int K    = blockIdx.x;
    const int kk   = blockIdx.y;
    const int bt   = blockIdx.z;
    const int t    = threadIdx.x;
    const int wave = t >> 6;
    const int lane = t & 63;
    const int ln   = lane & 15;
    const int quad = lane >> 4;
    const int row0 = bt * 128 + wave * 32;      // local (chunk) row base

    f32x4 acc[2][4];
#pragma unroll
    for (int mt = 0; mt < 2; ++mt)
#pragma unroll
        for (int nt = 0; nt < 4; ++nt) acc[mt][nt] = (f32x4){0.f, 0.f, 0.f, 0.f};

    const float* Wk = W + (size_t)(kk * NEXT + K) * DIN * DOUT;

    for (int dc = 0; dc < 4; ++dc) {
        __syncthreads();
        // stage x tile: 128 rows x 32 d (coalesced float4)
#pragma unroll
        for (int i = 0; i < 4; ++i) {
            const int f   = t + 256 * i;    // 0..1023 float4s
            const int row = f >> 3;
            const int d4  = f & 7;
            float4 v = *(const float4*)(x + ((size_t)(b0 + bt * 128 + row) * PRE + kk) * DIN + dc * 32 + d4 * 4);
            *(float4*)&xs[row * 40 + d4 * 4] = v;
        }
        // stage W slab 32x64, convert to packed bf16 hi|lo in fragment order
#pragma unroll
        for (int it = 0; it < 8; ++it) {
            const int e  = it * 256 + t;    // 0..2047
            const int dl = e >> 6;          // 0..31
            const int D  = e & 63;
            float v = Wk[(size_t)(dc * 32 + dl) * DOUT + D];
            unsigned short h = f2bf(v);
            unsigned short l = f2bf(v - bf2f(h));
            const int fr = ((D >> 4) * 64 + (dl >> 3) * 16 + (D & 15));
            wpk[fr * WFRAG_S + (dl & 7)] = (unsigned)h | ((unsigned)l << 16);
        }
        __syncthreads();

        // A fragments from xs + hi/lo split
        bf16x8 ah[2], al[2];
#pragma unroll
        for (int mt = 0; mt < 2; ++mt) {
            const float* xa = &xs[(wave * 32 + mt * 16 + ln) * 40 + quad * 8];
            float4 v0 = *(const float4*)xa;
            float4 v1 = *(const float4*)(xa + 4);
            float xv[8] = {v0.x, v0.y, v0.z, v0.w, v1.x, v1.y, v1.z, v1.w};
#pragma unroll
            for (int j = 0; j < 8; ++j) {
                unsigned short h = f2bf(xv[j]);
                ah[mt][j] = (short)h;
                al[mt][j] = (short)f2bf(xv[j] - bf2f(h));
            }
        }
        // B fragments from packed LDS (b64 reads, 8B-aligned at stride 40B)
        bf16x8 bh[4], bl[4];
#pragma unroll
        for (int nt = 0; nt < 4; ++nt) {
            const unsigned* wp = &wpk[(nt * 64 + quad * 16 + ln) * WFRAG_S];
            unsigned pk[8];
#pragma unroll
            for (int i2 = 0; i2 < 4; ++i2) *(uint2*)&pk[i2 * 2] = *(const uint2*)&wp[i2 * 2];
            union { bf16x8 v; unsigned u[4]; } BH, BL;
#pragma unroll
            for (int i2 = 0; i2 < 4; ++i2) {
                BH.u[i2] = (pk[2 * i2] & 0xffffu) | (pk[2 * i2 + 1] << 16);
                BL.u[i2] = (pk[2 * i2] >> 16) | (pk[2 * i2 + 1] & 0xffff0000u);
            }
            bh[nt] = BH.v; bl[nt] = BL.v;
        }
#pragma unroll
        for (int mt = 0; mt < 2; ++mt)
#pragma unroll
            for (int nt = 0; nt < 4; ++nt) {
                acc[mt][nt] = __builtin_amdgcn_mfma_f32_16x16x32_bf16(ah[mt], bh[nt], acc[mt][nt], 0, 0, 0);
                acc[mt][nt] = __builtin_amdgcn_mfma_f32_16x16x32_bf16(al[mt], bh[nt], acc[mt][nt], 0, 0, 0);
                acc[mt][nt] = __builtin_amdgcn_mfma_f32_16x16x32_bf16(ah[mt], bl[nt], acc[mt][nt], 0, 0, 0);
            }
    }

    // store natural fp32: C/D map col=ln, row=quad*4+r; 16 ln-lanes = 64B lines
#pragma unroll
    for (int mt = 0; mt < 2; ++mt)
#pragma unroll
        for (int nt = 0; nt < 4; ++nt) {
            const int D = nt * 16 + ln;
#pragma unroll
            for (int r = 0; r < 4; ++r) {
                const int row = row0 + mt * 16 + quad * 4 + r;
                p[((size_t)(row * PRE + kk) * NEXT + K) * DOUT + D] = acc[mt][nt][r];
            }
        }
}

// ---------------- Routing: 3 fused passes over fp32 p -------------------------
// 1024 thr (16 waves) per b -- was 512/8: route was latency-bound (hbm 31%,
// VALUBusy 7.8%, occupancy 19%), doubling resident waves doubles loads in
// flight (128 KB/CU). Wave w handles k = i*16+w, i in 0..3, 8-deep float4
// double-buffered prefetch unchanged. 16 per-wave partials don't fit LDS ->
// two-stage reduction: waves 0-7 write 8 buffers, waves 8-15 add into them.
// Load j: float4 idx j*64+lane -> K = j*4+(lane>>4), D-chunk m = lane&15.
// qsum stride 68 floats: b128 at 2 lanes/bank (free).
#define QSTR 68
#define QBUF (32 * QSTR)   // 2176 floats

__global__ __launch_bounds__(1024, 1) void route_kernel(const float* __restrict__ p,
                                                        float* __restrict__ out,
                                                        int b0)
{
    __shared__ float qpart[8 * QBUF];   // 68 KB shared partial-q buffers
    __shared__ float qsum[QBUF];        // 8.5 KB running Q = q1+..+q_{t-1}
    const int b    = blockIdx.x;
    const int t    = threadIdx.x;
    const int w    = t >> 6;      // 0..15
    const int lane = t & 63;
    const int g    = lane >> 4;   // 0..3
    const int m    = lane & 15;   // 0..15
    const float4* pb = (const float4*)(p + (size_t)b * (PRE * NEXT * DOUT));

    for (int idx = t; idx < QBUF; idx += 1024) qsum[idx] = 0.f;
    __syncthreads();

    for (int pass = 0; pass < 3; ++pass) {
        float4 qa[8];
#pragma unroll
        for (int j = 0; j < 8; ++j) qa[j] = (float4){0.f, 0.f, 0.f, 0.f};

        float4 pv[2][8];
        {
            const size_t sb = (size_t)w * 512;
#pragma unroll
            for (int j = 0; j < 8; ++j) pv[0][j] = pb[sb + j * 64 + lane];
        }
#pragma unroll
        for (int i = 0; i < 4; ++i) {
            const int buf = i & 1;
            if (i < 3) {
                const size_t sb = (size_t)((i + 1) * 16 + w) * 512;
#pragma unroll
                for (int j = 0; j < 8; ++j) pv[buf ^ 1][j] = pb[sb + j * 64 + lane];
            }
            float c[8];
            if (pass == 0) {
#pragma unroll
                for (int j = 0; j < 8; ++j) c[j] = 1.0f / 32.0f;
            } else {
                // logits = p . Q, Q streamed from LDS (b128, 16B-aligned)
#pragma unroll
                for (int j = 0; j < 8; ++j) {
                    float4 qv = *(const float4*)&qsum[(j * 4 + g) * QSTR + m * 4];
                    float d = pv[buf][j].x * qv.x + pv[buf][j].y * qv.y
                            + pv[buf][j].z * qv.z + pv[buf][j].w * qv.w;
                    d += __shfl_xor(d, 1);
                    d += __shfl_xor(d, 2);
                    d += __shfl_xor(d, 4);
                    d += __shfl_xor(d, 8);
                    c[j] = d;
                }
                float mx = c[0];
#pragma unroll
                for (int j = 1; j < 8; ++j) mx = fmaxf(mx, c[j]);
                mx = fmaxf(mx, __shfl_xor(mx, 16));
                mx = fmaxf(mx, __shfl_xor(mx, 32));
                float s = 0.f;
#pragma unroll
                for (int j = 0; j < 8; ++j) { c[j] = __expf(c[j] - mx); s += c[j]; }
                s += __shfl_xor(s, 16);
                s += __shfl_xor(s, 32);
                float inv = 1.0f / s;
#pragma unroll
                for (int j = 0; j < 8; ++j) c[j] *= inv;
            }
#pragma unroll
            for (int j = 0; j < 8; ++j) {
                qa[j].x += c[j] * pv[buf][j].x;
                qa[j].y += c[j] * pv[buf][j].y;
                qa[j].z += c[j] * pv[buf][j].z;
                qa[j].w += c[j] * pv[buf][j].w;
            }
        }
        // stage A: waves 0-7 write their partials
        if (w < 8) {
#pragma unroll
            for (int j = 0; j < 8; ++j)
                *(float4*)&qpart[w * QBUF + (j * 4 + g) * QSTR + m * 4] = qa[j];
        }
        __syncthreads();
        // stage B: waves 8-15 accumulate into buffer w-8 (disjoint slots)
        if (w >= 8) {
#pragma unroll
            for (int j = 0; j < 8; ++j) {
                float* qd = &qpart[(w - 8) * QBUF + (j * 4 + g) * QSTR + m * 4];
                float4 old = *(const float4*)qd;
                old.x += qa[j].x; old.y += qa[j].y; old.z += qa[j].z; old.w += qa[j].w;
                *(float4*)qd = old;
            }
        }
        __syncthreads();

        // tree-sum over 8 buffers + squash; thread t owns (K=t>>5, pair=t&31)
        {
            const int Kq = t >> 5, pr = t & 31;
            float vx = 0.f, vy = 0.f;
#pragma unroll
            for (int ww = 0; ww < 8; ++ww) {
                const float* s2p = &qpart[ww * QBUF + Kq * QSTR + pr * 2];
                vx += s2p[0]; vy += s2p[1];
            }
            float s2 = vx * vx + vy * vy;
            s2 += __shfl_xor(s2, 1);
            s2 += __shfl_xor(s2, 2);
            s2 += __shfl_xor(s2, 4);
            s2 += __shfl_xor(s2, 8);
            s2 += __shfl_xor(s2, 16);
            float fsc = s2 / ((1.f + s2) * sqrtf(s2 + 1e-8f));
            vx *= fsc; vy *= fsc;
            if (pass < 2) {
                float* qd = &qsum[Kq * QSTR + pr * 2];
                qd[0] += vx; qd[1] += vy;
            } else {
                float* od = out + (size_t)(b0 + b) * 2048 + Kq * 64 + pr * 2;
                od[0] = vx; od[1] = vy;
            }
        }
        if (pass < 2) __syncthreads();   // qsum visible + qpart reads done
    }
}

extern "C" void kernel_launch(void* const* d_in, const int* in_sizes, int n_in,
                              void* d_out, int out_size, void* d_ws, size_t ws_size,
                              hipStream_t stream) {
    const float* x = (const float*)d_in[0];
    const float* W = (const float*)d_in[1];
    float* out = (float*)d_out;
    float* p   = (float*)d_ws;    // p owns the whole workspace

    // full batch in one shot if ws >= 128 MiB (proven); else 2 chunks
    const int chunk = (ws_size >= (size_t)134217728) ? 256 : 128;

    for (int b0 = 0; b0 < BATCH; b0 += chunk) {
        gemm_kernel<<<dim3(NEXT, PRE, chunk / 128), 256, 0, stream>>>(x, W, p, b0);
        route_kernel<<<chunk, 1024, 0, stream>>>(p, out, b0);
    }
}